// Round 13
// baseline (6936.808 us; speedup 1.0000x reference)
//
#include <hip/hip_runtime.h>

#define N_NODES 100000
#define N_EDGES 1200000
#define DIM     64
#define N_LAYERS 3
#define N_GRAPHS 512
#define OUTD    192   // 3 * 64, concat layout
#define BN_EPS  1e-5f

#define NPB 64            // nodes per layer tile
#define LDS_PITCH 65      // +1 pad -> 2-way bank aliasing only (free)
#define MBLK 1563         // grid = #layer tiles; co-resident (<= 8/CU x 256)
#define NSHA 32           // BN shadow accumulators (~49 atomics/addr)

// ---- two-level binning geometry ----
#define BSHIFT 9
#define BUCK_NODES (1 << BSHIFT)                          // 512 nodes / bucket
#define NBUK ((N_NODES + BUCK_NODES - 1) / BUCK_NODES)    // 196
#define EPB 4096                                          // edges per partition block
#define NPBLK ((N_EDGES + EPB - 1) / EPB)                 // 293
#define MREM (MBLK & 31)                                  // 27

__device__ __forceinline__ unsigned short f2bf(float f) {
    unsigned u = __float_as_uint(f);
    return (unsigned short)((u + 0x7FFFu + ((u >> 16) & 1u)) >> 16);   // RNE
}
__device__ __forceinline__ float bf2f(unsigned short h) {
    return __uint_as_float(((unsigned)h) << 16);
}

// Two-level grid barrier: 32 shadow arrival counters (bc[0..31], ~49
// arrivals each -> R12-proven contention regime), master bc[32],
// generation bc[33]. SAFE because all MBLK blocks are co-resident
// (launch_bounds(256,8): VGPR<=64, LDS 17.2KB -> 8 blocks/CU, 2048 slots).
__device__ __forceinline__ void gbar(int* bc) {
    __syncthreads();
    if (threadIdx.x == 0) {
        int gen = __hip_atomic_load(&bc[33], __ATOMIC_RELAXED,
                                    __HIP_MEMORY_SCOPE_AGENT);
        __threadfence();
        int s = blockIdx.x & 31;
        int scnt = 48 + ((s < MREM) ? 1 : 0);
        int a = __hip_atomic_fetch_add(&bc[s], 1, __ATOMIC_ACQ_REL,
                                       __HIP_MEMORY_SCOPE_AGENT);
        if (a == scnt - 1) {
            __hip_atomic_store(&bc[s], 0, __ATOMIC_RELAXED,
                               __HIP_MEMORY_SCOPE_AGENT);
            int m = __hip_atomic_fetch_add(&bc[32], scnt, __ATOMIC_ACQ_REL,
                                           __HIP_MEMORY_SCOPE_AGENT);
            if (m + scnt == MBLK) {
                __hip_atomic_store(&bc[32], 0, __ATOMIC_RELAXED,
                                   __HIP_MEMORY_SCOPE_AGENT);
                __hip_atomic_store(&bc[33], gen + 1, __ATOMIC_RELEASE,
                                   __HIP_MEMORY_SCOPE_AGENT);
            }
        }
        while (__hip_atomic_load(&bc[33], __ATOMIC_ACQUIRE,
                                 __HIP_MEMORY_SCOPE_AGENT) == gen) {
            __builtin_amdgcn_s_sleep(4);
        }
        __threadfence();
    }
    __syncthreads();
}

// ---------------------------------------------------------------------------
// THE mega-kernel: prep+hist -> scatter -> CSR -> layer0 -> layer1 ->
// layer2 -> bn_pool, with 6 grid barriers. Every phase keeps the grid
// shape of its proven standalone kernel (R9 lesson: never throttle phase
// parallelism to protect a barrier).
__global__ void __launch_bounds__(256, 8) mega(
        const float* __restrict__ x0,
        const int* __restrict__ src, const int* __restrict__ dst,
        const float* __restrict__ ew, const int* __restrict__ batch,
        const float* __restrict__ W1, const float* __restrict__ b1,
        const float* __restrict__ W2, const float* __restrict__ b2,
        const float* __restrict__ gamma, const float* __restrict__ beta,
        float* __restrict__ W1T, float* __restrict__ W2T,
        int* __restrict__ hist, int2* __restrict__ pp,
        int* __restrict__ seg, int2* __restrict__ pe,
        unsigned short* __restrict__ x16a, unsigned short* __restrict__ x16b,
        float* __restrict__ accum /* [3][NSHA][128] */,
        float* __restrict__ xs, float* __restrict__ pooled,
        int* __restrict__ bc) {
    __shared__ float lds[NPB * LDS_PITCH];    // 16.64KB; reused by binning
    __shared__ float aff[128];
    int* ldsI = (int*)lds;
    int k = blockIdx.x, t = threadIdx.x;
    int lane = t & 63;
    int wid = __builtin_amdgcn_readfirstlane(t >> 6);

    // ================= Phase A: prep + per-chunk histogram =================
    {
        int gid = k * 256 + t;
        if (gid < N_LAYERS * DIM * DIM) {          // blocks 0..47: W transpose
            int l = gid >> 12;
            int r = gid & 4095;
            int j = r >> 6;
            int kk = r & 63;
            int dstp = (l << 12) + kk * DIM + j;
            W1T[dstp] = W1[gid];
            W2T[dstp] = W2[gid];
        }
        if (k == 48) {
            for (int i = t; i < N_LAYERS * NSHA * 128; i += 256) accum[i] = 0.0f;
        }
        if (k >= NPBLK) {                           // blocks 293..: zero pooled
            for (int i = (k - NPBLK) * 256 + t; i < N_GRAPHS * OUTD;
                 i += (MBLK - NPBLK) * 256)
                pooled[i] = 0.0f;
        }
        if (k < NPBLK) {
            if (t < NBUK) ldsI[t] = 0;
            __syncthreads();
            int e0 = k * EPB;
            int e1 = e0 + EPB; if (e1 > N_EDGES) e1 = N_EDGES;
            for (int e = e0 + t; e < e1; e += 256)
                atomicAdd(&ldsI[dst[e] >> BSHIFT], 1);
            __syncthreads();
            if (t < NBUK) hist[k * NBUK + t] = ldsI[t];
        }
    }
    gbar(bc);

    // ================= Phase B: scatter (blocks 0..292) =================
    if (k < NPBLK) {
        int* ps  = ldsI;          // [256]
        int* cur = ldsI + 256;    // [NBUK]
        int full = 0, pre = 0;
        if (t < NBUK) {
#pragma unroll 8
            for (int r = 0; r < NPBLK; ++r) {
                int hv = hist[r * NBUK + t];
                full += hv;
                pre += (r < k) ? hv : 0;
            }
        }
        ps[t] = (t < NBUK) ? full : 0;
        __syncthreads();
        int v = ps[t];
        for (int o = 1; o < 256; o <<= 1) {
            int add = (t >= o) ? ps[t - o] : 0;
            __syncthreads();
            ps[t] += add;
            __syncthreads();
        }
        if (t < NBUK) cur[t] = (ps[t] - v) + pre;
        __syncthreads();
        int bb = k * EPB;
        for (int i = t; i < EPB; i += 256) {
            int e = bb + i;
            if (e < N_EDGES) {
                int d = dst[e];
                int bk = d >> BSHIFT;
                int pos = atomicAdd(&cur[bk], 1);
                pp[pos] = make_int2(src[e] | ((d & (BUCK_NODES - 1)) << 17),
                                    __float_as_int(ew[e]));
            }
        }
    }
    gbar(bc);

    // ================= Phase C: per-bucket counting sort -> CSR ============
    if (k < NBUK) {
        int* cnt  = ldsI;         // [512]
        int* ssum = ldsI + 512;   // [256]
        int* btot = ldsI + 768;   // [256]
        int full = 0;
        if (t < NBUK) {
#pragma unroll 8
            for (int r = 0; r < NPBLK; ++r) full += hist[r * NBUK + t];
        }
        btot[t] = (t < NBUK) ? full : 0;
        __syncthreads();
        for (int o = 1; o < 256; o <<= 1) {
            int add = (t >= o) ? btot[t - o] : 0;
            __syncthreads();
            btot[t] += add;
            __syncthreads();
        }
        int eend = btot[k];
        int ebeg = (k == 0) ? 0 : btot[k - 1];
        cnt[t] = 0;
        cnt[t + 256] = 0;
        __syncthreads();
        for (int e = ebeg + t; e < eend; e += 256)
            atomicAdd(&cnt[pp[e].x >> 17], 1);
        __syncthreads();
        int c0 = cnt[2 * t], c1 = cnt[2 * t + 1];
        int ps2 = c0 + c1;
        ssum[t] = ps2;
        __syncthreads();
        int v = ps2;
        for (int o = 1; o < 256; o <<= 1) {
            int add = (t >= o) ? ssum[t - o] : 0;
            __syncthreads();
            ssum[t] += add;
            __syncthreads();
        }
        int excl = ssum[t] - v;
        int o0 = ebeg + excl;
        int o1 = o0 + c0;
        int n0 = (k << BSHIFT) + 2 * t;
        if (n0 < N_NODES) seg[n0] = o0;
        if (n0 + 1 < N_NODES) seg[n0 + 1] = o1;
        __syncthreads();
        cnt[2 * t] = o0;
        cnt[2 * t + 1] = o1;
        __syncthreads();
        for (int e = ebeg + t; e < eend; e += 256) {
            int2 p = pp[e];
            int pos = atomicAdd(&cnt[p.x >> 17], 1);
            pe[pos] = make_int2(p.x & 0x1FFFF, p.y);
        }
        if (k == 0 && t == 0) seg[N_NODES] = N_EDGES;
    }
    gbar(bc);

    // ================= Phases D/E/F: the 3 layers =================
    int slot = lane >> 4;
    int col  = lane & 15;
    int nbase = k * NPB;

    for (int l = 0; l < N_LAYERS; ++l) {
        const float* x_in = (l == 0) ? x0 : (xs + (size_t)(l - 1) * DIM);
        int xstride = (l == 0) ? DIM : OUTD;
        const unsigned short* x16in = (l == 1) ? x16b : x16a;
        unsigned short* x16out = (l == 0) ? x16b : x16a;
        int wr16 = (l < N_LAYERS - 1);
        const float* W1Tl = W1T + (size_t)l * DIM * DIM;
        const float* W2Tl = W2T + (size_t)l * DIM * DIM;
        const float* b1l = b1 + (size_t)l * DIM;
        const float* b2l = b2 + (size_t)l * DIM;
        float* accumCur = accum + (size_t)l * NSHA * 128;

        // ---- input BN affine from prev layer's shadows (l>0) ----
        if (l > 0) {
            const float* ap = accum + (size_t)(l - 1) * NSHA * 128;
            if (t < 64) {
                float s = 0.0f, q = 0.0f;
#pragma unroll 8
                for (int sh = 0; sh < NSHA; ++sh) {
                    s += ap[sh * 128 + t];
                    q += ap[sh * 128 + 64 + t];
                }
                float mu = s * (1.0f / N_NODES);
                float var = q * (1.0f / N_NODES) - mu * mu;
                float inv = 1.0f / sqrtf(var + BN_EPS);
                float sc = gamma[(l - 1) * 64 + t] * inv;
                aff[t] = sc;
                aff[64 + t] = beta[(l - 1) * 64 + t] - mu * sc;
            }
            __syncthreads();
        }
        float4 sc4 = make_float4(0.f, 0.f, 0.f, 0.f), sh4 = sc4;
        if (l > 0) {
            sc4 = make_float4(aff[col * 4], aff[col * 4 + 1],
                              aff[col * 4 + 2], aff[col * 4 + 3]);
            sh4 = make_float4(aff[64 + col * 4], aff[64 + col * 4 + 1],
                              aff[64 + col * 4 + 2], aff[64 + col * 4 + 3]);
        }

        // ---- gather (16 nodes per wave, quarter-wave float4 lanes) ----
        for (int nn = 0; nn < 16; ++nn) {
            int nl = wid * 16 + nn;
            int n = nbase + nl;
            float ax = 0.f, ay = 0.f, az = 0.f, aw = 0.f, wsa = 0.f;
            float bx = 0.f, by = 0.f, bz = 0.f, bw = 0.f, wsb = 0.f;
            if (n < N_NODES) {
                int beg = seg[n];
                int end = seg[n + 1];
#define GB_F32(EI, X, Y, Z, W, WS)                                             \
                if ((EI) < end) {                                              \
                    int2 p = pe[EI];                                           \
                    float w = __int_as_float(p.y);                             \
                    float4 fv =                                                \
                        ((const float4*)(x_in + (size_t)p.x * xstride))[col];  \
                    X = fmaf(w, fv.x, X); Y = fmaf(w, fv.y, Y);                \
                    Z = fmaf(w, fv.z, Z); W = fmaf(w, fv.w, W);                \
                    WS += w;                                                   \
                }
#define GB_B16(EI, X, Y, Z, W, WS)                                             \
                if ((EI) < end) {                                              \
                    int2 p = pe[EI];                                           \
                    float w = __int_as_float(p.y);                             \
                    ushort4 hv =                                               \
                        ((const ushort4*)(x16in + (size_t)p.x * DIM))[col];    \
                    X = fmaf(w, bf2f(hv.x), X); Y = fmaf(w, bf2f(hv.y), Y);    \
                    Z = fmaf(w, bf2f(hv.z), Z); W = fmaf(w, bf2f(hv.w), W);    \
                    WS += w;                                                   \
                }
                if (l == 0) {
                    for (int e = beg; e < end; e += 16) {
                        int e0 = e + slot;
                        GB_F32(e0,      ax, ay, az, aw, wsa)
                        GB_F32(e0 + 4,  bx, by, bz, bw, wsb)
                        GB_F32(e0 + 8,  ax, ay, az, aw, wsa)
                        GB_F32(e0 + 12, bx, by, bz, bw, wsb)
                    }
                } else {
                    for (int e = beg; e < end; e += 16) {
                        int e0 = e + slot;
                        GB_B16(e0,      ax, ay, az, aw, wsa)
                        GB_B16(e0 + 4,  bx, by, bz, bw, wsb)
                        GB_B16(e0 + 8,  ax, ay, az, aw, wsa)
                        GB_B16(e0 + 12, bx, by, bz, bw, wsb)
                    }
                }
#undef GB_F32
#undef GB_B16
            }
            float sx = ax + bx, sy = ay + by, sz = az + bz, sw = aw + bw;
            float ws = wsa + wsb;
            sx += __shfl_xor(sx, 16); sy += __shfl_xor(sy, 16);
            sz += __shfl_xor(sz, 16); sw += __shfl_xor(sw, 16);
            ws += __shfl_xor(ws, 16);
            sx += __shfl_xor(sx, 32); sy += __shfl_xor(sy, 32);
            sz += __shfl_xor(sz, 32); sw += __shfl_xor(sw, 32);
            ws += __shfl_xor(ws, 32);
            if (lane < 16) {
                float r0 = 0.f, r1 = 0.f, r2 = 0.f, r3 = 0.f;
                if (n < N_NODES) {
                    const float4* xr =
                        (const float4*)(x_in + (size_t)n * xstride) + col;
                    float4 s = *xr;                       // self term, f32
                    if (l > 0) {
                        float shw = 1.0f + ws;
                        r0 = fmaf(sc4.x, sx + s.x, sh4.x * shw);
                        r1 = fmaf(sc4.y, sy + s.y, sh4.y * shw);
                        r2 = fmaf(sc4.z, sz + s.z, sh4.z * shw);
                        r3 = fmaf(sc4.w, sw + s.w, sh4.w * shw);
                    } else {
                        r0 = sx + s.x; r1 = sy + s.y;
                        r2 = sz + s.z; r3 = sw + s.w;
                    }
                }
                int lb = nl * LDS_PITCH + col * 4;
                lds[lb] = r0; lds[lb + 1] = r1;
                lds[lb + 2] = r2; lds[lb + 3] = r3;
            }
        }
        __syncthreads();

        // ---- Stage 1 GEMM ----
        float h[16];
#pragma unroll
        for (int jj = 0; jj < 16; ++jj) h[jj] = b1l[wid * 16 + jj];
#pragma unroll 4
        for (int kk = 0; kk < DIM; ++kk) {
            float xv = lds[lane * LDS_PITCH + kk];
            const float* wr = W1Tl + kk * DIM + wid * 16;
#pragma unroll
            for (int jj = 0; jj < 16; ++jj) h[jj] = fmaf(xv, wr[jj], h[jj]);
        }
#pragma unroll
        for (int jj = 0; jj < 16; ++jj) h[jj] = fmaxf(h[jj], 0.0f);
        __syncthreads();
#pragma unroll
        for (int jj = 0; jj < 16; ++jj)
            lds[lane * LDS_PITCH + wid * 16 + jj] = h[jj];
        __syncthreads();

        // ---- Stage 2 GEMM ----
        float o[16];
#pragma unroll
        for (int jj = 0; jj < 16; ++jj) o[jj] = b2l[wid * 16 + jj];
#pragma unroll 4
        for (int kk = 0; kk < DIM; ++kk) {
            float hv = lds[lane * LDS_PITCH + kk];
            const float* wr = W2Tl + kk * DIM + wid * 16;
#pragma unroll
            for (int jj = 0; jj < 16; ++jj) o[jj] = fmaf(hv, wr[jj], o[jj]);
        }
        int n = nbase + lane;
        bool valid = (n < N_NODES);
#pragma unroll
        for (int jj = 0; jj < 16; ++jj) o[jj] = fmaxf(o[jj], 0.0f);
        if (valid) {
            float* orow = xs + (size_t)n * OUTD + l * DIM + wid * 16;
#pragma unroll
            for (int jj = 0; jj < 16; jj += 4) {
                *(float4*)(orow + jj) =
                    make_float4(o[jj], o[jj + 1], o[jj + 2], o[jj + 3]);
            }
            if (wr16) {
                unsigned short* hrow = x16out + (size_t)n * DIM + wid * 16;
#pragma unroll
                for (int jj = 0; jj < 16; jj += 4) {
                    ushort4 hq;
                    hq.x = f2bf(o[jj]);     hq.y = f2bf(o[jj + 1]);
                    hq.z = f2bf(o[jj + 2]); hq.w = f2bf(o[jj + 3]);
                    *(ushort4*)(hrow + jj) = hq;
                }
            }
        }

        // ---- BN shadow accumulation ----
        float my_s = 0.0f, my_q = 0.0f;
#pragma unroll
        for (int jj = 0; jj < 16; ++jj) {
            float v = valid ? o[jj] : 0.0f;
            float vs = v, vq = v * v;
#pragma unroll
            for (int m = 1; m < 64; m <<= 1) {
                vs += __shfl_xor(vs, m);
                vq += __shfl_xor(vq, m);
            }
            if (lane == jj) { my_s = vs; my_q = vq; }
        }
        if (lane < 16) {
            float* sh = accumCur + (size_t)(k & (NSHA - 1)) * 128;
            atomicAdd(&sh[wid * 16 + lane], my_s);
            atomicAdd(&sh[64 + wid * 16 + lane], my_q);
        }
        gbar(bc);
    }

    // ================= Phase G: bn_pool (2048 units over MBLK blocks) ======
    for (int u = k; u < N_GRAPHS * 4; u += MBLK) {
        int g = u >> 2, part = u & 3;
        int d = t;
        if (d < OUTD) {
            int l = d >> 6, dd = d & 63;
            float s = 0.0f, q = 0.0f;
#pragma unroll 8
            for (int sh = 0; sh < NSHA; ++sh) {
                s += accum[((size_t)l * NSHA + sh) * 128 + dd];
                q += accum[((size_t)l * NSHA + sh) * 128 + 64 + dd];
            }
            float mu = s * (1.0f / N_NODES);
            float var = q * (1.0f / N_NODES) - mu * mu;
            float inv = 1.0f / sqrtf(var + BN_EPS);
            float sc = gamma[l * 64 + dd] * inv;
            float sh2 = beta[l * 64 + dd] - mu * sc;
            int start, end;
            {
                int lo = 0, hi = N_NODES;
                while (lo < hi) { int m = (lo + hi) >> 1;
                    if (batch[m] < g) lo = m + 1; else hi = m; }
                start = lo;
            }
            {
                int lo = start, hi = N_NODES;
                while (lo < hi) { int m = (lo + hi) >> 1;
                    if (batch[m] <= g) lo = m + 1; else hi = m; }
                end = lo;
            }
            float acc = 0.0f;
            for (int nn2 = start + part; nn2 < end; nn2 += 4) {
                float* p = xs + (size_t)nn2 * OUTD + d;
                float v = fmaf(*p, sc, sh2);
                *p = v;
                acc += v;
            }
            atomicAdd(&pooled[(size_t)g * OUTD + d], acc);
        }
    }
}

// ---------------------------------------------------------------------------
extern "C" void kernel_launch(void* const* d_in, const int* in_sizes, int n_in,
                              void* d_out, int out_size, void* d_ws, size_t ws_size,
                              hipStream_t stream) {
    const float* x0    = (const float*)d_in[0];
    const int*   ei    = (const int*)d_in[1];
    const float* ew    = (const float*)d_in[2];
    const int*   batch = (const int*)d_in[3];
    const float* W1    = (const float*)d_in[5];
    const float* b1    = (const float*)d_in[6];
    const float* W2    = (const float*)d_in[7];
    const float* b2    = (const float*)d_in[8];
    const float* gamma = (const float*)d_in[9];
    const float* beta  = (const float*)d_in[10];

    float* pooled = (float*)d_out;                      // [512, 192]
    float* xs     = pooled + (size_t)N_GRAPHS * OUTD;   // [100000, 192]

    const int* src = ei;
    const int* dst = ei + N_EDGES;

    // Workspace (~36.5 MB): head persistent; tail union {pp|hist} / {x16}.
    int2*  pe     = (int2*)d_ws;                        // E  9.6 MB
    int*   seg    = (int*)(pe + N_EDGES);               // N+4
    float* W1T    = (float*)(seg + N_NODES + 4);
    float* W2T    = W1T + N_LAYERS * DIM * DIM;
    float* accum  = W2T + N_LAYERS * DIM * DIM;         // [3][NSHA][128]
    int*   bc     = (int*)(accum + (size_t)N_LAYERS * NSHA * 128);  // 64 ints
    // union region:
    char* uni = (char*)(bc + 64);
    int2*  pp     = (int2*)uni;                         // E (binning only)
    int*   hist   = (int*)(pp + N_EDGES);               // NPBLK*NBUK
    unsigned short* x16a = (unsigned short*)uni;        // N*64 bf16 (12.8 MB)
    unsigned short* x16b = x16a + (size_t)N_NODES * DIM;

    hipMemsetAsync(bc, 0, 64 * sizeof(int), stream);
    mega<<<MBLK, 256, 0, stream>>>(
        x0, src, dst, ew, batch, W1, b1, W2, b2, gamma, beta,
        W1T, W2T, hist, pp, seg, pe, x16a, x16b, accum, xs, pooled, bc);
}

// Round 14
// 520.058 us; speedup vs baseline: 13.3385x; 13.3385x over previous
//
#include <hip/hip_runtime.h>

#define N_NODES 100000
#define N_EDGES 1200000
#define DIM     64
#define N_LAYERS 3
#define N_GRAPHS 512
#define OUTD    192   // 3 * 64, concat layout
#define BN_EPS  1e-5f

#define NPB 64            // nodes per block in layer_kernel
#define LDS_PITCH 65      // +1 pad -> 2-way bank aliasing only (free)
#define NLBLK ((N_NODES + NPB - 1) / NPB)                 // 1563
#define NSHA 32           // BN shadow accumulators (~49 atomics/addr)

// ---- two-level binning geometry ----
#define BSHIFT 9
#define BUCK_NODES (1 << BSHIFT)                          // 512 nodes / bucket
#define NBUK ((N_NODES + BUCK_NODES - 1) / BUCK_NODES)    // 196
#define EPB 4096                                          // edges per partition block
#define NPBLK ((N_EDGES + EPB - 1) / EPB)                 // 293

__device__ __forceinline__ unsigned short f2bf(float f) {
    unsigned u = __float_as_uint(f);
    return (unsigned short)((u + 0x7FFFu + ((u >> 16) & 1u)) >> 16);   // RNE
}
__device__ __forceinline__ float bf2f(unsigned short h) {
    return __uint_as_float(((unsigned)h) << 16);
}

// ---------------------------------------------------------------------------
// K1: per-chunk bucket histogram + one-time prep folded in: blocks 0..47
// transpose W1/W2; block 48 zeroes accum[3][NSHA][128]; blocks 49..292
// zero pooled.
__global__ void __launch_bounds__(256) prep_hist(
        const float* __restrict__ W1, const float* __restrict__ W2,
        const int* __restrict__ dst,
        float* __restrict__ W1T, float* __restrict__ W2T,
        int* __restrict__ hist, float* __restrict__ accum,
        float* __restrict__ pooled) {
    __shared__ int h[NBUK];
    int k = blockIdx.x, t = threadIdx.x;
    int gid = k * 256 + t;
    if (gid < N_LAYERS * DIM * DIM) {          // blocks 0..47
        int l = gid >> 12;
        int r = gid & 4095;
        int j = r >> 6;
        int kk = r & 63;
        int dstp = (l << 12) + kk * DIM + j;
        W1T[dstp] = W1[gid];
        W2T[dstp] = W2[gid];
    }
    if (k == 48) {
        for (int i = t; i < N_LAYERS * NSHA * 128; i += 256) accum[i] = 0.0f;
    }
    if (k >= 49) {                              // blocks 49..292 zero pooled
        for (int i = (k - 49) * 256 + t; i < N_GRAPHS * OUTD; i += 244 * 256)
            pooled[i] = 0.0f;
    }
    // ---- histogram for this block's edge chunk ----
    if (t < NBUK) h[t] = 0;
    __syncthreads();
    int e0 = k * EPB;
    int e1 = e0 + EPB; if (e1 > N_EDGES) e1 = N_EDGES;
    for (int e = e0 + t; e < e1; e += 256) atomicAdd(&h[dst[e] >> BSHIFT], 1);
    __syncthreads();
    if (t < NBUK) hist[k * NBUK + t] = h[t];
}

// ---------------------------------------------------------------------------
// K2: scatter with INLINED base computation. Block k single-passes hist
// (L2-resident 230KB): column sums + prefix of rows < k, LDS scan, then
// scatters its chunk (disjoint deterministic ranges, LDS cursors).
__global__ void __launch_bounds__(256) part_scatter2(
        const int* __restrict__ src, const int* __restrict__ dst,
        const float* __restrict__ ew, const int* __restrict__ hist,
        int2* __restrict__ pp) {
    __shared__ int ps[256];
    __shared__ int cur[NBUK];
    int k = blockIdx.x, t = threadIdx.x;
    int full = 0, pre = 0;
    if (t < NBUK) {
#pragma unroll 8
        for (int r = 0; r < NPBLK; ++r) {
            int hv = hist[r * NBUK + t];
            full += hv;
            pre += (r < k) ? hv : 0;
        }
    }
    ps[t] = (t < NBUK) ? full : 0;
    __syncthreads();
    int v = ps[t];
    for (int o = 1; o < 256; o <<= 1) {
        int add = (t >= o) ? ps[t - o] : 0;
        __syncthreads();
        ps[t] += add;
        __syncthreads();
    }
    if (t < NBUK) cur[t] = (ps[t] - v) + pre;   // bucket start + chunk offset
    __syncthreads();
    int bb = k * EPB;
    for (int i = t; i < EPB; i += 256) {
        int e = bb + i;
        if (e < N_EDGES) {
            int d = dst[e];
            int bk = d >> BSHIFT;
            int pos = atomicAdd(&cur[bk], 1);
            pp[pos] = make_int2(src[e] | ((d & (BUCK_NODES - 1)) << 17),
                                __float_as_int(ew[e]));
        }
    }
}

// ---------------------------------------------------------------------------
// K3: per-bucket counting sort -> CSR; bucket begin/end from hist colsums.
__global__ void __launch_bounds__(256) csr_build2(
        const int2* __restrict__ pp, const int* __restrict__ hist,
        int* __restrict__ seg, int2* __restrict__ pe) {
    __shared__ int cnt[BUCK_NODES];
    __shared__ int ssum[256];
    __shared__ int btot[256];
    int b = blockIdx.x, t = threadIdx.x;
    int full = 0;
    if (t < NBUK) {
#pragma unroll 8
        for (int r = 0; r < NPBLK; ++r) full += hist[r * NBUK + t];
    }
    btot[t] = (t < NBUK) ? full : 0;
    __syncthreads();
    for (int o = 1; o < 256; o <<= 1) {
        int add = (t >= o) ? btot[t - o] : 0;
        __syncthreads();
        btot[t] += add;
        __syncthreads();
    }
    int eend = btot[b];                      // inclusive prefix, uniform
    int ebeg = (b == 0) ? 0 : btot[b - 1];
    cnt[t] = 0;
    cnt[t + 256] = 0;
    __syncthreads();
    for (int e = ebeg + t; e < eend; e += 256)
        atomicAdd(&cnt[pp[e].x >> 17], 1);
    __syncthreads();
    int c0 = cnt[2 * t], c1 = cnt[2 * t + 1];
    int ps = c0 + c1;
    ssum[t] = ps;
    __syncthreads();
    int v = ps;
    for (int o = 1; o < 256; o <<= 1) {
        int add = (t >= o) ? ssum[t - o] : 0;
        __syncthreads();
        ssum[t] += add;
        __syncthreads();
    }
    int excl = ssum[t] - v;           // exclusive over pairs
    int o0 = ebeg + excl;
    int o1 = o0 + c0;
    int n0 = (b << BSHIFT) + 2 * t;
    if (n0 < N_NODES) seg[n0] = o0;
    if (n0 + 1 < N_NODES) seg[n0 + 1] = o1;
    __syncthreads();                  // all cnt reads (c0,c1) retired
    cnt[2 * t] = o0;                  // reuse as cursors (global positions)
    cnt[2 * t + 1] = o1;
    __syncthreads();
    for (int e = ebeg + t; e < eend; e += 256) {
        int2 p = pp[e];
        int pos = atomicAdd(&cnt[p.x >> 17], 1);
        pe[pos] = make_int2(p.x & 0x1FFFF, p.y);   // plain (src, w)
    }
    if (b == 0 && t == 0) seg[N_NODES] = N_EDGES;
}

// ---------------------------------------------------------------------------
// Fused layer (R12 structure + PAIRED quarter-wave gather): nodes nn and
// nn+8 processed together -> 8 independent 16B loads in flight per wave
// (was 4); self-term loads hoisted before the edge loop (was after the
// 10-shuffle reduce, on the critical path). Everything else unchanged.
template <int BF16IN>
__global__ void __launch_bounds__(256) layer_kernel(
    const float* __restrict__ x_in, int xstride,          // f32 rows
    const unsigned short* __restrict__ x16in,             // bf16 neighbor rows
    unsigned short* __restrict__ x16out, int wr16,
    const int* __restrict__ seg,     // CSR offsets (N+1)
    const int2* __restrict__ pe,     // (src, w)
    const float* __restrict__ accumPrev,   // [NSHA][128] prev sums|sumsq
    const float* __restrict__ gprev, const float* __restrict__ bprev,
    const float* __restrict__ W1T, const float* __restrict__ b1,
    const float* __restrict__ W2T, const float* __restrict__ b2,
    float* __restrict__ out /* xs base + layer*64, row stride OUTD */,
    float* __restrict__ accumCur /* [NSHA][128] this layer's sums|sumsq */) {
    __shared__ float lds[NPB * LDS_PITCH];
    __shared__ float aff[128];
    int t = threadIdx.x;
    int lane = t & 63;
    int wid = __builtin_amdgcn_readfirstlane(t >> 6);   // wave id 0..3, SGPR
    int nbase = blockIdx.x * NPB;

    int slot = lane >> 4;            // 0..3: which edge of a 4-group
    int col  = lane & 15;            // which float4 of the row

    // ---- prologue: input BN affine from prev-layer shadows (BF16IN only) --
    if (BF16IN) {
        if (t < 64) {
            float s = 0.0f, q = 0.0f;
#pragma unroll 8
            for (int sh = 0; sh < NSHA; ++sh) {
                s += accumPrev[sh * 128 + t];
                q += accumPrev[sh * 128 + 64 + t];
            }
            float mu = s * (1.0f / N_NODES);
            float var = q * (1.0f / N_NODES) - mu * mu;
            float inv = 1.0f / sqrtf(var + BN_EPS);
            float sc = gprev[t] * inv;
            aff[t] = sc;
            aff[64 + t] = bprev[t] - mu * sc;
        }
        __syncthreads();
    }
    float4 sc4, sh4;
    if (BF16IN) {
        sc4 = make_float4(aff[col * 4], aff[col * 4 + 1],
                          aff[col * 4 + 2], aff[col * 4 + 3]);
        sh4 = make_float4(aff[64 + col * 4], aff[64 + col * 4 + 1],
                          aff[64 + col * 4 + 2], aff[64 + col * 4 + 3]);
    }

    // ---- Phase 1: PAIRED gather (nodes nn, nn+8 together; 8 pairs/wave) --
#define GBODY(EI, END, X, Y, Z, W, WS)                                         \
    if ((EI) < (END)) {                                                        \
        int2 p = pe[EI];                                                       \
        float w = __int_as_float(p.y);                                         \
        float vx, vy, vz, vw;                                                  \
        if (BF16IN) {                                                          \
            ushort4 hv = ((const ushort4*)(x16in + (size_t)p.x * DIM))[col];   \
            vx = bf2f(hv.x); vy = bf2f(hv.y);                                  \
            vz = bf2f(hv.z); vw = bf2f(hv.w);                                  \
        } else {                                                               \
            float4 fv = ((const float4*)(x_in + (size_t)p.x * xstride))[col];  \
            vx = fv.x; vy = fv.y; vz = fv.z; vw = fv.w;                        \
        }                                                                      \
        X = fmaf(w, vx, X); Y = fmaf(w, vy, Y);                                \
        Z = fmaf(w, vz, Z); W = fmaf(w, vw, W);                                \
        WS += w;                                                               \
    }
    for (int nn = 0; nn < 8; ++nn) {
        int nlA = wid * 16 + nn;
        int nlB = nlA + 8;
        int nA = nbase + nlA;
        int nB = nbase + nlB;
        bool vA = (nA < N_NODES), vB = (nB < N_NODES);
        int begA = 0, endA = 0, begB = 0, endB = 0;
        if (vA) { begA = seg[nA]; endA = seg[nA + 1]; }
        if (vB) { begB = seg[nB]; endB = seg[nB + 1]; }
        // self terms issued early (off the critical path)
        float4 sfA = make_float4(0.f, 0.f, 0.f, 0.f), sfB = sfA;
        if (vA) sfA = ((const float4*)(x_in + (size_t)nA * xstride))[col];
        if (vB) sfB = ((const float4*)(x_in + (size_t)nB * xstride))[col];
        float axA = 0.f, ayA = 0.f, azA = 0.f, awA = 0.f;
        float bxA = 0.f, byA = 0.f, bzA = 0.f, bwA = 0.f;
        float axB = 0.f, ayB = 0.f, azB = 0.f, awB = 0.f;
        float bxB = 0.f, byB = 0.f, bzB = 0.f, bwB = 0.f;
        float wsaA = 0.f, wsbA = 0.f, wsaB = 0.f, wsbB = 0.f;
        for (int ii = 0; begA + ii < endA || begB + ii < endB; ii += 16) {
            int eA = begA + ii + slot;
            int eB = begB + ii + slot;
            GBODY(eA,      endA, axA, ayA, azA, awA, wsaA)
            GBODY(eB,      endB, axB, ayB, azB, awB, wsaB)
            GBODY(eA + 4,  endA, bxA, byA, bzA, bwA, wsbA)
            GBODY(eB + 4,  endB, bxB, byB, bzB, bwB, wsbB)
            GBODY(eA + 8,  endA, axA, ayA, azA, awA, wsaA)
            GBODY(eB + 8,  endB, axB, ayB, azB, awB, wsaB)
            GBODY(eA + 12, endA, bxA, byA, bzA, bwA, wsbA)
            GBODY(eB + 12, endB, bxB, byB, bzB, bwB, wsbB)
        }
        float sxA = axA + bxA, syA = ayA + byA, szA = azA + bzA, swA = awA + bwA;
        float sxB = axB + bxB, syB = ayB + byB, szB = azB + bzB, swB = awB + bwB;
        float wsA = wsaA + wsbA, wsB = wsaB + wsbB;
        // interleaved 4-slot reductions (two independent shuffle chains)
        sxA += __shfl_xor(sxA, 16); sxB += __shfl_xor(sxB, 16);
        syA += __shfl_xor(syA, 16); syB += __shfl_xor(syB, 16);
        szA += __shfl_xor(szA, 16); szB += __shfl_xor(szB, 16);
        swA += __shfl_xor(swA, 16); swB += __shfl_xor(swB, 16);
        wsA += __shfl_xor(wsA, 16); wsB += __shfl_xor(wsB, 16);
        sxA += __shfl_xor(sxA, 32); sxB += __shfl_xor(sxB, 32);
        syA += __shfl_xor(syA, 32); syB += __shfl_xor(syB, 32);
        szA += __shfl_xor(szA, 32); szB += __shfl_xor(szB, 32);
        swA += __shfl_xor(swA, 32); swB += __shfl_xor(swB, 32);
        wsA += __shfl_xor(wsA, 32); wsB += __shfl_xor(wsB, 32);
        if (lane < 16) {
            float r0A = 0.f, r1A = 0.f, r2A = 0.f, r3A = 0.f;
            float r0B = 0.f, r1B = 0.f, r2B = 0.f, r3B = 0.f;
            if (vA) {
                if (BF16IN) {
                    float shw = 1.0f + wsA;
                    r0A = fmaf(sc4.x, sxA + sfA.x, sh4.x * shw);
                    r1A = fmaf(sc4.y, syA + sfA.y, sh4.y * shw);
                    r2A = fmaf(sc4.z, szA + sfA.z, sh4.z * shw);
                    r3A = fmaf(sc4.w, swA + sfA.w, sh4.w * shw);
                } else {
                    r0A = sxA + sfA.x; r1A = syA + sfA.y;
                    r2A = szA + sfA.z; r3A = swA + sfA.w;
                }
            }
            if (vB) {
                if (BF16IN) {
                    float shw = 1.0f + wsB;
                    r0B = fmaf(sc4.x, sxB + sfB.x, sh4.x * shw);
                    r1B = fmaf(sc4.y, syB + sfB.y, sh4.y * shw);
                    r2B = fmaf(sc4.z, szB + sfB.z, sh4.z * shw);
                    r3B = fmaf(sc4.w, swB + sfB.w, sh4.w * shw);
                } else {
                    r0B = sxB + sfB.x; r1B = syB + sfB.y;
                    r2B = szB + sfB.z; r3B = swB + sfB.w;
                }
            }
            int lbA = nlA * LDS_PITCH + col * 4;
            int lbB = nlB * LDS_PITCH + col * 4;
            lds[lbA] = r0A; lds[lbA + 1] = r1A;
            lds[lbA + 2] = r2A; lds[lbA + 3] = r3A;
            lds[lbB] = r0B; lds[lbB + 1] = r1B;
            lds[lbB + 2] = r2B; lds[lbB + 3] = r3B;
        }
    }
#undef GBODY
    __syncthreads();

    // ---- Stage 1 GEMM: hidden = relu(xin @ W1^T + b1) ----
    float h[16];
#pragma unroll
    for (int jj = 0; jj < 16; ++jj) h[jj] = b1[wid * 16 + jj];
#pragma unroll 4
    for (int k = 0; k < DIM; ++k) {
        float xv = lds[lane * LDS_PITCH + k];
        const float* wr = W1T + k * DIM + wid * 16;   // uniform -> s_load
#pragma unroll
        for (int jj = 0; jj < 16; ++jj) h[jj] = fmaf(xv, wr[jj], h[jj]);
    }
#pragma unroll
    for (int jj = 0; jj < 16; ++jj) h[jj] = fmaxf(h[jj], 0.0f);
    __syncthreads();          // all lds (xin) reads done
#pragma unroll
    for (int jj = 0; jj < 16; ++jj) lds[lane * LDS_PITCH + wid * 16 + jj] = h[jj];
    __syncthreads();

    // ---- Stage 2 GEMM: o = relu(hidden @ W2^T + b2) ----
    float o[16];
#pragma unroll
    for (int jj = 0; jj < 16; ++jj) o[jj] = b2[wid * 16 + jj];
#pragma unroll 4
    for (int k = 0; k < DIM; ++k) {
        float hv = lds[lane * LDS_PITCH + k];
        const float* wr = W2T + k * DIM + wid * 16;
#pragma unroll
        for (int jj = 0; jj < 16; ++jj) o[jj] = fmaf(hv, wr[jj], o[jj]);
    }
    int n = nbase + lane;
    bool valid = (n < N_NODES);
#pragma unroll
    for (int jj = 0; jj < 16; ++jj) o[jj] = fmaxf(o[jj], 0.0f);
    if (valid) {
        float* orow = out + (size_t)n * OUTD + wid * 16;
#pragma unroll
        for (int jj = 0; jj < 16; jj += 4) {
            *(float4*)(orow + jj) = make_float4(o[jj], o[jj + 1], o[jj + 2], o[jj + 3]);
        }
        if (wr16) {
            unsigned short* hrow = x16out + (size_t)n * DIM + wid * 16;
#pragma unroll
            for (int jj = 0; jj < 16; jj += 4) {
                ushort4 hq;
                hq.x = f2bf(o[jj]);     hq.y = f2bf(o[jj + 1]);
                hq.z = f2bf(o[jj + 2]); hq.w = f2bf(o[jj + 3]);
                *(ushort4*)(hrow + jj) = hq;
            }
        }
    }

    // ---- BN stat partials: butterfly over 64 lanes; atomics go to the
    // block's shadow copy (blockIdx&31) -> ~49 serialized adds per address.
    float my_s = 0.0f, my_q = 0.0f;
#pragma unroll
    for (int jj = 0; jj < 16; ++jj) {
        float v = valid ? o[jj] : 0.0f;
        float vs = v, vq = v * v;
#pragma unroll
        for (int m = 1; m < 64; m <<= 1) {
            vs += __shfl_xor(vs, m);
            vq += __shfl_xor(vq, m);
        }
        if (lane == jj) { my_s = vs; my_q = vq; }
    }
    if (lane < 16) {
        float* sh = accumCur + (size_t)(blockIdx.x & (NSHA - 1)) * 128;
        atomicAdd(&sh[wid * 16 + lane], my_s);
        atomicAdd(&sh[64 + wid * 16 + lane], my_q);
    }
}

// ---------------------------------------------------------------------------
// Final pass: reduce shadow accumulators in-thread -> BN affine, apply to
// xs IN PLACE, add-pool per graph.
__global__ void bn_pool(float* __restrict__ xs,
                        const int* __restrict__ batch,
                        const float* __restrict__ accum /* [3][NSHA][128] */,
                        const float* __restrict__ gamma /* [3][64] */,
                        const float* __restrict__ beta  /* [3][64] */,
                        float* __restrict__ pooled) {
    int g = blockIdx.x;
    int part = blockIdx.y;   // 0..3
    int d = threadIdx.x;     // 0..191
    int l = d >> 6, dd = d & 63;
    float s = 0.0f, q = 0.0f;
#pragma unroll 8
    for (int sh = 0; sh < NSHA; ++sh) {
        s += accum[((size_t)l * NSHA + sh) * 128 + dd];
        q += accum[((size_t)l * NSHA + sh) * 128 + 64 + dd];
    }
    float mu = s * (1.0f / N_NODES);
    float var = q * (1.0f / N_NODES) - mu * mu;
    float inv = 1.0f / sqrtf(var + BN_EPS);
    float sc = gamma[l * 64 + dd] * inv;
    float sh2 = beta[l * 64 + dd] - mu * sc;
    int start, end;
    {
        int lo = 0, hi = N_NODES;
        while (lo < hi) { int m = (lo + hi) >> 1; if (batch[m] < g) lo = m + 1; else hi = m; }
        start = lo;
    }
    {
        int lo = start, hi = N_NODES;
        while (lo < hi) { int m = (lo + hi) >> 1; if (batch[m] <= g) lo = m + 1; else hi = m; }
        end = lo;
    }
    float acc = 0.0f;
    for (int n = start + part; n < end; n += 4) {
        float* p = xs + (size_t)n * OUTD + d;
        float v = fmaf(*p, sc, sh2);
        *p = v;
        acc += v;
    }
    atomicAdd(&pooled[(size_t)g * OUTD + d], acc);
}

// ---------------------------------------------------------------------------
extern "C" void kernel_launch(void* const* d_in, const int* in_sizes, int n_in,
                              void* d_out, int out_size, void* d_ws, size_t ws_size,
                              hipStream_t stream) {
    const float* x0    = (const float*)d_in[0];
    const int*   ei    = (const int*)d_in[1];
    const float* ew    = (const float*)d_in[2];
    const int*   batch = (const int*)d_in[3];
    const float* W1    = (const float*)d_in[5];
    const float* b1    = (const float*)d_in[6];
    const float* W2    = (const float*)d_in[7];
    const float* b2    = (const float*)d_in[8];
    const float* gamma = (const float*)d_in[9];
    const float* beta  = (const float*)d_in[10];

    float* pooled = (float*)d_out;                      // [512, 192]
    float* xs     = pooled + (size_t)N_GRAPHS * OUTD;   // [100000, 192]

    const int* src = ei;
    const int* dst = ei + N_EDGES;

    // Workspace (~36.5 MB): head persistent; tail union {pp|hist} / {x16}.
    int2*  pe     = (int2*)d_ws;                        // E  9.6 MB
    int*   seg    = (int*)(pe + N_EDGES);               // N+4
    float* W1T    = (float*)(seg + N_NODES + 4);
    float* W2T    = W1T + N_LAYERS * DIM * DIM;
    float* accum  = W2T + N_LAYERS * DIM * DIM;         // [3][NSHA][128] 48KB
    // union region:
    char* uni = (char*)(accum + (size_t)N_LAYERS * NSHA * 128 + 16);
    int2*  pp     = (int2*)uni;                         // E (binning only)
    int*   hist   = (int*)(pp + N_EDGES);               // NPBLK*NBUK
    unsigned short* x16a = (unsigned short*)uni;        // N*64 bf16 (12.8 MB)
    unsigned short* x16b = x16a + (size_t)N_NODES * DIM;

    // K1: histogram + transpose + zero accum + zero pooled   (1 dispatch)
    prep_hist<<<NPBLK, 256, 0, stream>>>(W1, W2, dst, W1T, W2T, hist,
                                         accum, pooled);
    // K2: scatter with inlined bases                        (1 dispatch)
    part_scatter2<<<NPBLK, 256, 0, stream>>>(src, dst, ew, hist, pp);
    // K3: per-bucket counting sort -> CSR                   (1 dispatch)
    csr_build2<<<NBUK, 256, 0, stream>>>(pp, hist, seg, pe);

    for (int i = 0; i < N_LAYERS; ++i) {
        const float* xin = (i == 0) ? x0 : (xs + (size_t)(i - 1) * DIM);
        int xstride = (i == 0) ? DIM : OUTD;
        const unsigned short* x16in = (i == 1) ? x16b : x16a;
        unsigned short* x16out = (i == 0) ? x16b : x16a;
        int wr16 = (i < N_LAYERS - 1) ? 1 : 0;
        const float* accumPrev = accum + (size_t)(i - 1) * NSHA * 128;
        float* accumCur = accum + (size_t)i * NSHA * 128;

        if (i == 0) {
            layer_kernel<0><<<NLBLK, 256, 0, stream>>>(
                xin, xstride, x16in, x16out, wr16, seg, pe,
                accum, gamma, beta,                       // dummies for i==0
                W1T, b1, W2T, b2, xs, accumCur);
        } else {
            layer_kernel<1><<<NLBLK, 256, 0, stream>>>(
                xin, xstride, x16in, x16out, wr16, seg, pe,
                accumPrev, gamma + (size_t)(i - 1) * DIM,
                beta + (size_t)(i - 1) * DIM,
                W1T + (size_t)i * DIM * DIM, b1 + (size_t)i * DIM,
                W2T + (size_t)i * DIM * DIM, b2 + (size_t)i * DIM,
                xs + (size_t)i * DIM, accumCur);
        }
    }

    dim3 pgrid(N_GRAPHS, 4);
    bn_pool<<<pgrid, OUTD, 0, stream>>>(xs, batch, accum, gamma, beta, pooled);
}

// Round 15
// 451.031 us; speedup vs baseline: 15.3799x; 1.1530x over previous
//
#include <hip/hip_runtime.h>

#define N_NODES 100000
#define N_EDGES 1200000
#define DIM     64
#define N_LAYERS 3
#define N_GRAPHS 512
#define OUTD    192   // 3 * 64, concat layout
#define BN_EPS  1e-5f

#define NPB 64            // nodes per block in layer_kernel
#define LDS_PITCH 65      // +1 pad -> 2-way bank aliasing only (free)
#define NLBLK ((N_NODES + NPB - 1) / NPB)                 // 1563
#define NSHA 32           // BN shadow accumulators (~49 atomics/addr)

// ---- two-level binning geometry ----
#define BSHIFT 9
#define BUCK_NODES (1 << BSHIFT)                          // 512 nodes / bucket
#define NBUK ((N_NODES + BUCK_NODES - 1) / BUCK_NODES)    // 196
#define EPB 4096                                          // edges per partition block
#define NPBLK ((N_EDGES + EPB - 1) / EPB)                 // 293

__device__ __forceinline__ unsigned short f2bf(float f) {
    unsigned u = __float_as_uint(f);
    return (unsigned short)((u + 0x7FFFu + ((u >> 16) & 1u)) >> 16);   // RNE
}
__device__ __forceinline__ float bf2f(unsigned short h) {
    return __uint_as_float(((unsigned)h) << 16);
}

// ---------------------------------------------------------------------------
// K1: per-chunk bucket histogram + one-time prep folded in: blocks 0..47
// transpose W1/W2; block 48 zeroes accum[3][NSHA][128]; blocks 49..292
// zero pooled.
__global__ void __launch_bounds__(256) prep_hist(
        const float* __restrict__ W1, const float* __restrict__ W2,
        const int* __restrict__ dst,
        float* __restrict__ W1T, float* __restrict__ W2T,
        int* __restrict__ hist, float* __restrict__ accum,
        float* __restrict__ pooled) {
    __shared__ int h[NBUK];
    int k = blockIdx.x, t = threadIdx.x;
    int gid = k * 256 + t;
    if (gid < N_LAYERS * DIM * DIM) {          // blocks 0..47
        int l = gid >> 12;
        int r = gid & 4095;
        int j = r >> 6;
        int kk = r & 63;
        int dstp = (l << 12) + kk * DIM + j;
        W1T[dstp] = W1[gid];
        W2T[dstp] = W2[gid];
    }
    if (k == 48) {
        for (int i = t; i < N_LAYERS * NSHA * 128; i += 256) accum[i] = 0.0f;
    }
    if (k >= 49) {                              // blocks 49..292 zero pooled
        for (int i = (k - 49) * 256 + t; i < N_GRAPHS * OUTD; i += 244 * 256)
            pooled[i] = 0.0f;
    }
    // ---- histogram for this block's edge chunk ----
    if (t < NBUK) h[t] = 0;
    __syncthreads();
    int e0 = k * EPB;
    int e1 = e0 + EPB; if (e1 > N_EDGES) e1 = N_EDGES;
    for (int e = e0 + t; e < e1; e += 256) atomicAdd(&h[dst[e] >> BSHIFT], 1);
    __syncthreads();
    if (t < NBUK) hist[k * NBUK + t] = h[t];
}

// ---------------------------------------------------------------------------
// K2: scatter with INLINED base computation. Block k single-passes hist
// (L2-resident 230KB): column sums + prefix of rows < k, LDS scan, then
// scatters its chunk (disjoint deterministic ranges, LDS cursors).
__global__ void __launch_bounds__(256) part_scatter2(
        const int* __restrict__ src, const int* __restrict__ dst,
        const float* __restrict__ ew, const int* __restrict__ hist,
        int2* __restrict__ pp) {
    __shared__ int ps[256];
    __shared__ int cur[NBUK];
    int k = blockIdx.x, t = threadIdx.x;
    int full = 0, pre = 0;
    if (t < NBUK) {
#pragma unroll 8
        for (int r = 0; r < NPBLK; ++r) {
            int hv = hist[r * NBUK + t];
            full += hv;
            pre += (r < k) ? hv : 0;
        }
    }
    ps[t] = (t < NBUK) ? full : 0;
    __syncthreads();
    int v = ps[t];
    for (int o = 1; o < 256; o <<= 1) {
        int add = (t >= o) ? ps[t - o] : 0;
        __syncthreads();
        ps[t] += add;
        __syncthreads();
    }
    if (t < NBUK) cur[t] = (ps[t] - v) + pre;   // bucket start + chunk offset
    __syncthreads();
    int bb = k * EPB;
    for (int i = t; i < EPB; i += 256) {
        int e = bb + i;
        if (e < N_EDGES) {
            int d = dst[e];
            int bk = d >> BSHIFT;
            int pos = atomicAdd(&cur[bk], 1);
            pp[pos] = make_int2(src[e] | ((d & (BUCK_NODES - 1)) << 17),
                                __float_as_int(ew[e]));
        }
    }
}

// ---------------------------------------------------------------------------
// K3: per-bucket counting sort -> CSR; bucket begin/end from hist colsums.
__global__ void __launch_bounds__(256) csr_build2(
        const int2* __restrict__ pp, const int* __restrict__ hist,
        int* __restrict__ seg, int2* __restrict__ pe) {
    __shared__ int cnt[BUCK_NODES];
    __shared__ int ssum[256];
    __shared__ int btot[256];
    int b = blockIdx.x, t = threadIdx.x;
    int full = 0;
    if (t < NBUK) {
#pragma unroll 8
        for (int r = 0; r < NPBLK; ++r) full += hist[r * NBUK + t];
    }
    btot[t] = (t < NBUK) ? full : 0;
    __syncthreads();
    for (int o = 1; o < 256; o <<= 1) {
        int add = (t >= o) ? btot[t - o] : 0;
        __syncthreads();
        btot[t] += add;
        __syncthreads();
    }
    int eend = btot[b];                      // inclusive prefix, uniform
    int ebeg = (b == 0) ? 0 : btot[b - 1];
    cnt[t] = 0;
    cnt[t + 256] = 0;
    __syncthreads();
    for (int e = ebeg + t; e < eend; e += 256)
        atomicAdd(&cnt[pp[e].x >> 17], 1);
    __syncthreads();
    int c0 = cnt[2 * t], c1 = cnt[2 * t + 1];
    int ps = c0 + c1;
    ssum[t] = ps;
    __syncthreads();
    int v = ps;
    for (int o = 1; o < 256; o <<= 1) {
        int add = (t >= o) ? ssum[t - o] : 0;
        __syncthreads();
        ssum[t] += add;
        __syncthreads();
    }
    int excl = ssum[t] - v;           // exclusive over pairs
    int o0 = ebeg + excl;
    int o1 = o0 + c0;
    int n0 = (b << BSHIFT) + 2 * t;
    if (n0 < N_NODES) seg[n0] = o0;
    if (n0 + 1 < N_NODES) seg[n0 + 1] = o1;
    __syncthreads();                  // all cnt reads (c0,c1) retired
    cnt[2 * t] = o0;                  // reuse as cursors (global positions)
    cnt[2 * t + 1] = o1;
    __syncthreads();
    for (int e = ebeg + t; e < eend; e += 256) {
        int2 p = pp[e];
        int pos = atomicAdd(&cnt[p.x >> 17], 1);
        pe[pos] = make_int2(p.x & 0x1FFFF, p.y);   // plain (src, w)
    }
    if (b == 0 && t == 0) seg[N_NODES] = N_EDGES;
}

// ---------------------------------------------------------------------------
// Fused layer (R12 structure, measured best): quarter-wave float4 gather;
// BF16IN=0 -> layer 0: f32 neighbors + identity input affine; BF16IN=1 ->
// bf16 neighbors + input affine reduced IN-PROLOGUE from the prev layer's
// NSHA shadow accumulators. Epilogue atomicAdds BN partials into shadow
// (blockIdx&31) -> ~49 atomics/address.
template <int BF16IN>
__global__ void __launch_bounds__(256) layer_kernel(
    const float* __restrict__ x_in, int xstride,          // f32 rows
    const unsigned short* __restrict__ x16in,             // bf16 neighbor rows
    unsigned short* __restrict__ x16out, int wr16,
    const int* __restrict__ seg,     // CSR offsets (N+1)
    const int2* __restrict__ pe,     // (src, w)
    const float* __restrict__ accumPrev,   // [NSHA][128] prev sums|sumsq
    const float* __restrict__ gprev, const float* __restrict__ bprev,
    const float* __restrict__ W1T, const float* __restrict__ b1,
    const float* __restrict__ W2T, const float* __restrict__ b2,
    float* __restrict__ out /* xs base + layer*64, row stride OUTD */,
    float* __restrict__ accumCur /* [NSHA][128] this layer's sums|sumsq */) {
    __shared__ float lds[NPB * LDS_PITCH];
    __shared__ float aff[128];
    int t = threadIdx.x;
    int lane = t & 63;
    int wid = __builtin_amdgcn_readfirstlane(t >> 6);   // wave id 0..3, SGPR
    int nbase = blockIdx.x * NPB;

    int slot = lane >> 4;            // 0..3: which edge of a 4-group
    int col  = lane & 15;            // which float4 of the row

    // ---- prologue: input BN affine from prev-layer shadows (BF16IN only) --
    if (BF16IN) {
        if (t < 64) {
            float s = 0.0f, q = 0.0f;
#pragma unroll 8
            for (int sh = 0; sh < NSHA; ++sh) {
                s += accumPrev[sh * 128 + t];
                q += accumPrev[sh * 128 + 64 + t];
            }
            float mu = s * (1.0f / N_NODES);
            float var = q * (1.0f / N_NODES) - mu * mu;
            float inv = 1.0f / sqrtf(var + BN_EPS);
            float sc = gprev[t] * inv;
            aff[t] = sc;
            aff[64 + t] = bprev[t] - mu * sc;
        }
        __syncthreads();
    }
    float4 sc4, sh4;
    if (BF16IN) {
        sc4 = make_float4(aff[col * 4], aff[col * 4 + 1],
                          aff[col * 4 + 2], aff[col * 4 + 3]);
        sh4 = make_float4(aff[64 + col * 4], aff[64 + col * 4 + 1],
                          aff[64 + col * 4 + 2], aff[64 + col * 4 + 3]);
    }

    // ---- Phase 1: gather (16 nodes per wave, node id wave-uniform) ----
    for (int nn = 0; nn < 16; ++nn) {
        int nl = wid * 16 + nn;
        int n = nbase + nl;
        float ax = 0.f, ay = 0.f, az = 0.f, aw = 0.f, wsa = 0.f;
        float bx = 0.f, by = 0.f, bz = 0.f, bw = 0.f, wsb = 0.f;
        if (n < N_NODES) {
            int beg = seg[n];
            int end = seg[n + 1];
#define GBODY(EI, X, Y, Z, W, WS)                                              \
            if ((EI) < end) {                                                  \
                int2 p = pe[EI];                                               \
                float w = __int_as_float(p.y);                                 \
                float vx, vy, vz, vw;                                          \
                if (BF16IN) {                                                  \
                    ushort4 hv =                                               \
                        ((const ushort4*)(x16in + (size_t)p.x * DIM))[col];    \
                    vx = bf2f(hv.x); vy = bf2f(hv.y);                          \
                    vz = bf2f(hv.z); vw = bf2f(hv.w);                          \
                } else {                                                       \
                    float4 fv =                                                \
                        ((const float4*)(x_in + (size_t)p.x * xstride))[col];  \
                    vx = fv.x; vy = fv.y; vz = fv.z; vw = fv.w;                \
                }                                                              \
                X = fmaf(w, vx, X); Y = fmaf(w, vy, Y);                        \
                Z = fmaf(w, vz, Z); W = fmaf(w, vw, W);                        \
                WS += w;                                                       \
            }
            for (int e = beg; e < end; e += 16) {
                int e0 = e + slot;
                GBODY(e0,      ax, ay, az, aw, wsa)
                GBODY(e0 + 4,  bx, by, bz, bw, wsb)
                GBODY(e0 + 8,  ax, ay, az, aw, wsa)
                GBODY(e0 + 12, bx, by, bz, bw, wsb)
            }
#undef GBODY
        }
        float sx = ax + bx, sy = ay + by, sz = az + bz, sw = aw + bw;
        float ws = wsa + wsb;
        // reduce across the 4 slots (lane bits 4,5); all lanes get totals
        sx += __shfl_xor(sx, 16); sy += __shfl_xor(sy, 16);
        sz += __shfl_xor(sz, 16); sw += __shfl_xor(sw, 16);
        ws += __shfl_xor(ws, 16);
        sx += __shfl_xor(sx, 32); sy += __shfl_xor(sy, 32);
        sz += __shfl_xor(sz, 32); sw += __shfl_xor(sw, 32);
        ws += __shfl_xor(ws, 32);
        if (lane < 16) {
            float r0 = 0.f, r1 = 0.f, r2 = 0.f, r3 = 0.f;
            if (n < N_NODES) {
                const float4* xr =
                    (const float4*)(x_in + (size_t)n * xstride) + col;
                float4 s = *xr;                       // self term, f32
                if (BF16IN) {
                    float shw = 1.0f + ws;
                    r0 = fmaf(sc4.x, sx + s.x, sh4.x * shw);
                    r1 = fmaf(sc4.y, sy + s.y, sh4.y * shw);
                    r2 = fmaf(sc4.z, sz + s.z, sh4.z * shw);
                    r3 = fmaf(sc4.w, sw + s.w, sh4.w * shw);
                } else {                              // identity affine
                    r0 = sx + s.x; r1 = sy + s.y;
                    r2 = sz + s.z; r3 = sw + s.w;
                }
            }
            int lb = nl * LDS_PITCH + col * 4;
            lds[lb] = r0; lds[lb + 1] = r1; lds[lb + 2] = r2; lds[lb + 3] = r3;
        }
    }
    __syncthreads();

    // ---- Stage 1 GEMM: hidden = relu(xin @ W1^T + b1) ----
    float h[16];
#pragma unroll
    for (int jj = 0; jj < 16; ++jj) h[jj] = b1[wid * 16 + jj];
#pragma unroll 4
    for (int k = 0; k < DIM; ++k) {
        float xv = lds[lane * LDS_PITCH + k];
        const float* wr = W1T + k * DIM + wid * 16;   // uniform -> s_load
#pragma unroll
        for (int jj = 0; jj < 16; ++jj) h[jj] = fmaf(xv, wr[jj], h[jj]);
    }
#pragma unroll
    for (int jj = 0; jj < 16; ++jj) h[jj] = fmaxf(h[jj], 0.0f);
    __syncthreads();          // all lds (xin) reads done
#pragma unroll
    for (int jj = 0; jj < 16; ++jj) lds[lane * LDS_PITCH + wid * 16 + jj] = h[jj];
    __syncthreads();

    // ---- Stage 2 GEMM: o = relu(hidden @ W2^T + b2) ----
    float o[16];
#pragma unroll
    for (int jj = 0; jj < 16; ++jj) o[jj] = b2[wid * 16 + jj];
#pragma unroll 4
    for (int k = 0; k < DIM; ++k) {
        float hv = lds[lane * LDS_PITCH + k];
        const float* wr = W2T + k * DIM + wid * 16;
#pragma unroll
        for (int jj = 0; jj < 16; ++jj) o[jj] = fmaf(hv, wr[jj], o[jj]);
    }
    int n = nbase + lane;
    bool valid = (n < N_NODES);
#pragma unroll
    for (int jj = 0; jj < 16; ++jj) o[jj] = fmaxf(o[jj], 0.0f);
    if (valid) {
        float* orow = out + (size_t)n * OUTD + wid * 16;
#pragma unroll
        for (int jj = 0; jj < 16; jj += 4) {
            *(float4*)(orow + jj) = make_float4(o[jj], o[jj + 1], o[jj + 2], o[jj + 3]);
        }
        if (wr16) {
            unsigned short* hrow = x16out + (size_t)n * DIM + wid * 16;
#pragma unroll
            for (int jj = 0; jj < 16; jj += 4) {
                ushort4 hq;
                hq.x = f2bf(o[jj]);     hq.y = f2bf(o[jj + 1]);
                hq.z = f2bf(o[jj + 2]); hq.w = f2bf(o[jj + 3]);
                *(ushort4*)(hrow + jj) = hq;
            }
        }
    }

    // ---- BN stat partials: butterfly over 64 lanes; atomics go to the
    // block's shadow copy (blockIdx&31) -> ~49 serialized adds per address.
    float my_s = 0.0f, my_q = 0.0f;
#pragma unroll
    for (int jj = 0; jj < 16; ++jj) {
        float v = valid ? o[jj] : 0.0f;
        float vs = v, vq = v * v;
#pragma unroll
        for (int m = 1; m < 64; m <<= 1) {
            vs += __shfl_xor(vs, m);
            vq += __shfl_xor(vq, m);
        }
        if (lane == jj) { my_s = vs; my_q = vq; }
    }
    if (lane < 16) {
        float* sh = accumCur + (size_t)(blockIdx.x & (NSHA - 1)) * 128;
        atomicAdd(&sh[wid * 16 + lane], my_s);
        atomicAdd(&sh[64 + wid * 16 + lane], my_q);
    }
}

// ---------------------------------------------------------------------------
// Final pass: reduce shadow accumulators in-thread -> BN affine, apply to
// xs IN PLACE, add-pool per graph.
__global__ void bn_pool(float* __restrict__ xs,
                        const int* __restrict__ batch,
                        const float* __restrict__ accum /* [3][NSHA][128] */,
                        const float* __restrict__ gamma /* [3][64] */,
                        const float* __restrict__ beta  /* [3][64] */,
                        float* __restrict__ pooled) {
    int g = blockIdx.x;
    int part = blockIdx.y;   // 0..3
    int d = threadIdx.x;     // 0..191
    int l = d >> 6, dd = d & 63;
    float s = 0.0f, q = 0.0f;
#pragma unroll 8
    for (int sh = 0; sh < NSHA; ++sh) {
        s += accum[((size_t)l * NSHA + sh) * 128 + dd];
        q += accum[((size_t)l * NSHA + sh) * 128 + 64 + dd];
    }
    float mu = s * (1.0f / N_NODES);
    float var = q * (1.0f / N_NODES) - mu * mu;
    float inv = 1.0f / sqrtf(var + BN_EPS);
    float sc = gamma[l * 64 + dd] * inv;
    float sh2 = beta[l * 64 + dd] - mu * sc;
    int start, end;
    {
        int lo = 0, hi = N_NODES;
        while (lo < hi) { int m = (lo + hi) >> 1; if (batch[m] < g) lo = m + 1; else hi = m; }
        start = lo;
    }
    {
        int lo = start, hi = N_NODES;
        while (lo < hi) { int m = (lo + hi) >> 1; if (batch[m] <= g) lo = m + 1; else hi = m; }
        end = lo;
    }
    float acc = 0.0f;
    for (int n = start + part; n < end; n += 4) {
        float* p = xs + (size_t)n * OUTD + d;
        float v = fmaf(*p, sc, sh2);
        *p = v;
        acc += v;
    }
    atomicAdd(&pooled[(size_t)g * OUTD + d], acc);
}

// ---------------------------------------------------------------------------
extern "C" void kernel_launch(void* const* d_in, const int* in_sizes, int n_in,
                              void* d_out, int out_size, void* d_ws, size_t ws_size,
                              hipStream_t stream) {
    const float* x0    = (const float*)d_in[0];
    const int*   ei    = (const int*)d_in[1];
    const float* ew    = (const float*)d_in[2];
    const int*   batch = (const int*)d_in[3];
    const float* W1    = (const float*)d_in[5];
    const float* b1    = (const float*)d_in[6];
    const float* W2    = (const float*)d_in[7];
    const float* b2    = (const float*)d_in[8];
    const float* gamma = (const float*)d_in[9];
    const float* beta  = (const float*)d_in[10];

    float* pooled = (float*)d_out;                      // [512, 192]
    float* xs     = pooled + (size_t)N_GRAPHS * OUTD;   // [100000, 192]

    const int* src = ei;
    const int* dst = ei + N_EDGES;

    // Workspace (~36.5 MB): head persistent; tail union {pp|hist} / {x16}.
    int2*  pe     = (int2*)d_ws;                        // E  9.6 MB
    int*   seg    = (int*)(pe + N_EDGES);               // N+4
    float* W1T    = (float*)(seg + N_NODES + 4);
    float* W2T    = W1T + N_LAYERS * DIM * DIM;
    float* accum  = W2T + N_LAYERS * DIM * DIM;         // [3][NSHA][128] 48KB
    // union region:
    char* uni = (char*)(accum + (size_t)N_LAYERS * NSHA * 128 + 16);
    int2*  pp     = (int2*)uni;                         // E (binning only)
    int*   hist   = (int*)(pp + N_EDGES);               // NPBLK*NBUK
    unsigned short* x16a = (unsigned short*)uni;        // N*64 bf16 (12.8 MB)
    unsigned short* x16b = x16a + (size_t)N_NODES * DIM;

    // K1: histogram + transpose + zero accum + zero pooled   (1 dispatch)
    prep_hist<<<NPBLK, 256, 0, stream>>>(W1, W2, dst, W1T, W2T, hist,
                                         accum, pooled);
    // K2: scatter with inlined bases                        (1 dispatch)
    part_scatter2<<<NPBLK, 256, 0, stream>>>(src, dst, ew, hist, pp);
    // K3: per-bucket counting sort -> CSR                   (1 dispatch)
    csr_build2<<<NBUK, 256, 0, stream>>>(pp, hist, seg, pe);

    for (int i = 0; i < N_LAYERS; ++i) {
        const float* xin = (i == 0) ? x0 : (xs + (size_t)(i - 1) * DIM);
        int xstride = (i == 0) ? DIM : OUTD;
        const unsigned short* x16in = (i == 1) ? x16b : x16a;
        unsigned short* x16out = (i == 0) ? x16b : x16a;
        int wr16 = (i < N_LAYERS - 1) ? 1 : 0;
        const float* accumPrev = accum + (size_t)(i - 1) * NSHA * 128;
        float* accumCur = accum + (size_t)i * NSHA * 128;

        if (i == 0) {
            layer_kernel<0><<<NLBLK, 256, 0, stream>>>(
                xin, xstride, x16in, x16out, wr16, seg, pe,
                accum, gamma, beta,                       // dummies for i==0
                W1T, b1, W2T, b2, xs, accumCur);
        } else {
            layer_kernel<1><<<NLBLK, 256, 0, stream>>>(
                xin, xstride, x16in, x16out, wr16, seg, pe,
                accumPrev, gamma + (size_t)(i - 1) * DIM,
                beta + (size_t)(i - 1) * DIM,
                W1T + (size_t)i * DIM * DIM, b1 + (size_t)i * DIM,
                W2T + (size_t)i * DIM * DIM, b2 + (size_t)i * DIM,
                xs + (size_t)i * DIM, accumCur);
        }
    }

    dim3 pgrid(N_GRAPHS, 4);
    bn_pool<<<pgrid, OUTD, 0, stream>>>(xs, batch, accum, gamma, beta, pooled);
}